// Round 9
// baseline (119.759 us; speedup 1.0000x reference)
//
#include <hip/hip_runtime.h>
#include <hip/hip_bf16.h>
#include <stdint.h>

// Chamfer distance, B=2, N=M=8192, fp32 3-D points — MFMA, two transposed passes.
//
// d2[n][m] = |p_n|^2 + |g_m|^2 - 2 p_n.g_m inside v_mfma_f32_32x32x16_bf16 via
// split-bf16 (hi+lo), K=16 (encoding + A/B/C layouts verified R3-R8: absmax 0.0):
//   A_k: [-2hx,-2hy,-2hz, -2hx,-2hy,-2hz, -2lx,-2ly,-2lz, -2lx,-2ly,-2lz, h2,l2,1,1]
//   B_k: [ hx, hy, hz,  lx, ly, lz,  hx, hy, hz,  lx, ly, lz,  1,1, h2,l2]
//
// R9 — MEASUREMENT ROUND (sacrificial). R8's x2 duplication showed marginal
// mfma cost ~8.4us/pass, leaving ~25us/replay unaccounted; the mfma kernel has
// NEVER appeared in the top-5 profile rows (harness 256MB poison-fills sit at
// 39-40us and everything of mine is just below). rep x8 (grid z=32) makes the
// mfma dispatch >=67us -> guaranteed top-of-profile with full counters
// (MfmaUtil / VALUBusy / Occupancy / VGPR / bank-conflict / FETCH). All reps
// compute and write byte-identical WROW values — deterministic. Everything
// else identical to R8.

typedef __attribute__((ext_vector_type(8))) short short8v;
typedef __attribute__((ext_vector_type(16))) float f32x16;

#define NP 8192
#define NCHUNK 8
#define CHUNKCOLS 1024
#define ROWS_PER_BLOCK 256       // 4 waves x 64 rows
#define SCALE 0.390625f          // 80^2 / (2 * 8192)

// ws byte offsets
#define OFF_ROW 0u         // float[4 db][8 chunk][8192]   row-min partials (1 MB)
#define OFF_B   4194304u   // uint4[4 db][2 half][8192]    B k-half planes (1 MB)

__device__ inline uint32_t f2u(float f){ union{float f;uint32_t u;}c; c.f=f; return c.u; }
__device__ inline float u2f(uint32_t u){ union{float f;uint32_t u;}c; c.u=u; return c.f; }
__device__ inline uint16_t bfr(float f){ uint32_t u=f2u(f); return (uint16_t)((u + 0x7FFFu + ((u>>16)&1u))>>16); }
__device__ inline float bff(uint16_t s){ return u2f(((uint32_t)s)<<16); }
__device__ inline float min3f(float a,float b,float c){ return fminf(fminf(a,b),c); }

__device__ inline short8v encodeA(float x, float y, float z, int half) {
  const uint16_t hx=bfr(x), hy=bfr(y), hz=bfr(z);
  const uint16_t lx=bfr(x-bff(hx)), ly=bfr(y-bff(hy)), lz=bfr(z-bff(hz));
  const float s2 = fmaf(x,x,fmaf(y,y,z*z));
  const uint16_t h2=bfr(s2), l2=bfr(s2-bff(h2));
  const uint16_t nhx=bfr(-2.f*bff(hx)), nhy=bfr(-2.f*bff(hy)), nhz=bfr(-2.f*bff(hz));
  const uint16_t nlx=bfr(-2.f*bff(lx)), nly=bfr(-2.f*bff(ly)), nlz=bfr(-2.f*bff(lz));
  union{ ushort u[16]; short8v s8[2]; } A;
  A.u[0]=nhx; A.u[1]=nhy; A.u[2]=nhz; A.u[3]=nhx; A.u[4]=nhy; A.u[5]=nhz;
  A.u[6]=nlx; A.u[7]=nly; A.u[8]=nlz; A.u[9]=nlx; A.u[10]=nly; A.u[11]=nlz;
  A.u[12]=h2; A.u[13]=l2; A.u[14]=0x3F80; A.u[15]=0x3F80;
  return half ? A.s8[1] : A.s8[0];
}

// ---------------- prep: pack B k-half planes ----------------
__global__ __launch_bounds__(256) void prep_kernel(
    const float* __restrict__ pred, const float* __restrict__ gt,
    float* __restrict__ out, uint8_t* __restrict__ ws) {
  const int tid = blockIdx.x*256 + (int)threadIdx.x;   // 0..65535
  if (tid == 0) out[0] = 0.0f;
  const int col  = tid & 8191;
  const int half = (tid >> 13) & 1;
  const int db   = tid >> 14;          // dir*2 + b
  const int dir = db >> 1, b = db & 1;

  const float* src = (dir == 0 ? gt : pred) + ((size_t)b*NP + col)*3;
  const float x = src[0], y = src[1], z = src[2];

  const uint16_t hx=bfr(x), hy=bfr(y), hz=bfr(z);
  const uint16_t lx=bfr(x-bff(hx)), ly=bfr(y-bff(hy)), lz=bfr(z-bff(hz));
  const float s2 = fmaf(x,x,fmaf(y,y,z*z));
  const uint16_t h2=bfr(s2), l2=bfr(s2-bff(h2));
  union{ ushort u[16]; uint4 v[2]; } B;
  B.u[0]=hx; B.u[1]=hy; B.u[2]=hz; B.u[3]=lx; B.u[4]=ly; B.u[5]=lz;
  B.u[6]=hx; B.u[7]=hy; B.u[8]=hz; B.u[9]=lx; B.u[10]=ly; B.u[11]=lz;
  B.u[12]=0x3F80; B.u[13]=0x3F80; B.u[14]=h2; B.u[15]=l2;

  uint4* BP = (uint4*)(ws + OFF_B);
  BP[(size_t)tid] = half ? B.v[1] : B.v[0];   // [(db*2+half)*NP + col]
}

// ---------------- main MFMA kernel ----------------
__global__ __launch_bounds__(256, 2) void chamfer_mfma_kernel(
    const float* __restrict__ pred, const float* __restrict__ gt,
    uint8_t* __restrict__ ws) {
  const int wave = threadIdx.x >> 6, lane = threadIdx.x & 63;
  const int half = lane >> 5, l31 = lane & 31;
  const int rowblk = blockIdx.x;            // 0..31
  const int chunk  = blockIdx.y;            // 0..7
  const int db     = blockIdx.z & 3;        // dir*2 + b  (z>>2 = rep 0..7:
                                            // byte-identical work, diagnostic)
  const int dir = db >> 1, b = db & 1;

  __shared__ uint4 ldsB[2][CHUNKCOLS];      // 32 KB, single-buffered

  // ---- stage the whole chunk (both k-half planes), 8 uint4 per thread
  const uint4* BP = (const uint4*)(ws + OFF_B) + (size_t)db*2*NP
                    + (size_t)chunk*CHUNKCOLS;
#pragma unroll
  for (int k = 0; k < 8; ++k) {
    const int gidx = k*256 + (int)threadIdx.x;   // 0..2047
    const int h = gidx >> 10, c = gidx & 1023;
    ((uint4*)ldsB)[gidx] = BP[(size_t)h*NP + c];
  }

  // ---- inline A-encode for the wave's 2 row-fragments (overlaps staging)
  const float* abase = (dir == 0 ? pred : gt) + (size_t)b*NP*3;
  const int row0 = rowblk*ROWS_PER_BLOCK + wave*64 + l31;  // and row0+32
  short8v afrag0, afrag1;
  {
    const float* a0 = abase + (size_t)row0*3;
    afrag0 = encodeA(a0[0], a0[1], a0[2], half);
    const float* a1 = abase + (size_t)(row0+32)*3;
    afrag1 = encodeA(a1[0], a1[1], a1[2], half);
  }

  float rm0[16], rm1[16];
#pragma unroll
  for (int i=0;i<16;++i) { rm0[i] = 3.4e38f; rm1[i] = 3.4e38f; }
  const f32x16 zero = {};

  __syncthreads();

  // ---- 16 steps x {2 ds_read_b128, 4 MFMA, 32 v_min3}; runtime loop, unroll 2
  const uint4* lb = &ldsB[half][l31];
#pragma unroll 2
  for (int t = 0; t < 32; t += 2) {
    const short8v b0 = *(const short8v*)(lb + t*32);
    const short8v b1 = *(const short8v*)(lb + t*32 + 32);
    const f32x16 m00 = __builtin_amdgcn_mfma_f32_32x32x16_bf16(afrag0, b0, zero, 0,0,0);
    const f32x16 m01 = __builtin_amdgcn_mfma_f32_32x32x16_bf16(afrag0, b1, zero, 0,0,0);
    const f32x16 m10 = __builtin_amdgcn_mfma_f32_32x32x16_bf16(afrag1, b0, zero, 0,0,0);
    const f32x16 m11 = __builtin_amdgcn_mfma_f32_32x32x16_bf16(afrag1, b1, zero, 0,0,0);
#pragma unroll
    for (int i=0;i<16;++i) {
      rm0[i] = min3f(rm0[i], m00[i], m01[i]);
      rm1[i] = min3f(rm1[i], m10[i], m11[i]);
    }
  }

  // ---- row-min across the 32 cols (lanes) per half
#pragma unroll
  for (int i=0;i<16;++i) {
    float v0 = rm0[i], v1 = rm1[i];
    v0 = fminf(v0, __shfl_xor(v0, 1));  v1 = fminf(v1, __shfl_xor(v1, 1));
    v0 = fminf(v0, __shfl_xor(v0, 2));  v1 = fminf(v1, __shfl_xor(v1, 2));
    v0 = fminf(v0, __shfl_xor(v0, 4));  v1 = fminf(v1, __shfl_xor(v1, 4));
    v0 = fminf(v0, __shfl_xor(v0, 8));  v1 = fminf(v1, __shfl_xor(v1, 8));
    v0 = fminf(v0, __shfl_xor(v0, 16)); v1 = fminf(v1, __shfl_xor(v1, 16));
    rm0[i] = v0; rm1[i] = v1;
  }
  if (l31 == 0) {
    // C/D map (verified): row = (i&3) + 8*(i>>2) + 4*half
    float* wr = (float*)(ws + OFF_ROW) + ((size_t)db*NCHUNK + chunk)*NP
                + rowblk*ROWS_PER_BLOCK + wave*64 + half*4;
#pragma unroll
    for (int i=0;i<16;++i) {
      const int r = (i&3) + 8*(i>>2);
      wr[r] = rm0[i];
      wr[r + 32] = rm1[i];
    }
  }
}

// ---------------- final reduce ----------------
__global__ __launch_bounds__(256) void reduce_kernel(
    const uint8_t* __restrict__ ws, float* __restrict__ out) {
  const float* WROW = (const float*)(ws + OFF_ROW);
  const int tid = blockIdx.x*256 + (int)threadIdx.x;  // 0..32767
  const int db = tid >> 13, q = tid & 8191;

  const float* pr = WROW + (size_t)db*NCHUNK*NP + q;
  float mn = 3.4e38f;
#pragma unroll
  for (int k = 0; k < NCHUNK; ++k) mn = fminf(mn, pr[(size_t)k*NP]);
  float sum = fmaxf(mn, 0.0f);  // clamp == ref's maximum(d2,0)

#pragma unroll
  for (int off=32; off>0; off>>=1) sum += __shfl_down(sum, off);
  __shared__ float red[4];
  if ((threadIdx.x & 63) == 0) red[threadIdx.x >> 6] = sum;
  __syncthreads();
  if (threadIdx.x == 0) atomicAdd(out, (red[0]+red[1]+red[2]+red[3]) * SCALE);
}

extern "C" void kernel_launch(void* const* d_in, const int* in_sizes, int n_in,
                              void* d_out, int out_size, void* d_ws, size_t ws_size,
                              hipStream_t stream) {
  const float* pred = (const float*)d_in[0];
  const float* gt = (const float*)d_in[1];
  float* out = (float*)d_out;
  uint8_t* ws = (uint8_t*)d_ws;

  prep_kernel<<<256, 256, 0, stream>>>(pred, gt, out, ws);
  // z x8: z>>2 = rep (diagnostic duplicate, identical work), z&3 = db
  chamfer_mfma_kernel<<<dim3(NP/ROWS_PER_BLOCK, NCHUNK, 32), 256, 0, stream>>>(pred, gt, ws);
  reduce_kernel<<<128, 256, 0, stream>>>(ws, out);
}

// Round 11
// 33.572 us; speedup vs baseline: 3.5673x; 3.5673x over previous
//
#include <hip/hip_runtime.h>
#include <hip/hip_bf16.h>
#include <stdint.h>

// Chamfer distance, B=2, N=M=8192, fp32 3-D points — MFMA, two transposed passes.
//
// d2[t][q] = |t|^2 + |q|^2 - 2 t.q inside v_mfma_f32_32x32x16_bf16 via
// split-bf16 (hi+lo), K=16 (encoding verified R3-R9: absmax 0.0):
//   A_k (target): [-2h(xyz), -2h(xyz), -2l(xyz), -2l(xyz), h2, l2, 1, 1]
//   B_k (query) : [  h(xyz),   l(xyz),   h(xyz),   l(xyz), 1, 1, h2, l2]
//
// R11 vs R10 (asm-hazard FAIL) / R9 (13.3us, VGPR=52, accvgpr storm):
// OPERAND SWAP: mfma(A=targets, B=queries) -> each lane's 16 result regs are
// 16 targets of ONE query (col=lane&31). Running min per lane = ONE scalar;
// fold = pure min3 tree (8/MFMA, the structural VALU floor, 2:1 vs MFMA);
// epilogue = 2 shfl_xor + 1 store (was 320 bpermutes). Live state ~90 floats
// -> no AGPR pressure -> no accvgpr copies. NO inline asm anywhere (R10
// lesson: asm reading MFMA dst regs skips hazard waits).

typedef __attribute__((ext_vector_type(8))) short short8v;
typedef __attribute__((ext_vector_type(16))) float f32x16;

#define NP 8192
#define NCHUNK 8
#define CHUNKCOLS 1024           // targets per chunk (staged in LDS)
#define SCALE 0.390625f          // 80^2 / (2 * 8192)

// ws byte offsets
#define OFF_ROW 0u         // float[4 db][8 chunk][8192]  per-chunk query mins (1 MB)
#define OFF_A   2097152u   // uint4[4 db][2 half][8192]   target planes (1 MB)
#define OFF_B   4194304u   // uint4[4 db][2 half][8192]   query planes (1 MB)

__device__ inline uint32_t f2u(float f){ union{float f;uint32_t u;}c; c.f=f; return c.u; }
__device__ inline float u2f(uint32_t u){ union{float f;uint32_t u;}c; c.u=u; return c.f; }
__device__ inline uint16_t bfr(float f){ uint32_t u=f2u(f); return (uint16_t)((u + 0x7FFFu + ((u>>16)&1u))>>16); }
__device__ inline float bff(uint16_t s){ return u2f(((uint32_t)s)<<16); }
__device__ inline float min3f(float a,float b,float c){ return fminf(fminf(a,b),c); }

// fold 16 MFMA result regs + rm -> rm : exactly 8 v_min3
__device__ inline float fold16(float rm, const f32x16& m) {
  const float a = min3f(m[0],m[1],m[2]);
  const float b = min3f(m[3],m[4],m[5]);
  const float c = min3f(m[6],m[7],m[8]);
  const float d = min3f(m[9],m[10],m[11]);
  const float e = min3f(m[12],m[13],m[14]);
  const float f = min3f(a,b,c);
  const float g = min3f(d,e,m[15]);
  return min3f(rm, f, g);
}

__device__ inline uint4 packA(float x, float y, float z, int half) {
  const uint16_t hx=bfr(x), hy=bfr(y), hz=bfr(z);
  const uint16_t lx=bfr(x-bff(hx)), ly=bfr(y-bff(hy)), lz=bfr(z-bff(hz));
  const float s2 = fmaf(x,x,fmaf(y,y,z*z));
  const uint16_t h2=bfr(s2), l2=bfr(s2-bff(h2));
  const uint16_t nhx=bfr(-2.f*bff(hx)), nhy=bfr(-2.f*bff(hy)), nhz=bfr(-2.f*bff(hz));
  const uint16_t nlx=bfr(-2.f*bff(lx)), nly=bfr(-2.f*bff(ly)), nlz=bfr(-2.f*bff(lz));
  union{ ushort u[16]; uint4 v[2]; } A;
  A.u[0]=nhx; A.u[1]=nhy; A.u[2]=nhz; A.u[3]=nhx; A.u[4]=nhy; A.u[5]=nhz;
  A.u[6]=nlx; A.u[7]=nly; A.u[8]=nlz; A.u[9]=nlx; A.u[10]=nly; A.u[11]=nlz;
  A.u[12]=h2; A.u[13]=l2; A.u[14]=0x3F80; A.u[15]=0x3F80;
  return A.v[half];
}

__device__ inline uint4 packB(float x, float y, float z, int half) {
  const uint16_t hx=bfr(x), hy=bfr(y), hz=bfr(z);
  const uint16_t lx=bfr(x-bff(hx)), ly=bfr(y-bff(hy)), lz=bfr(z-bff(hz));
  const float s2 = fmaf(x,x,fmaf(y,y,z*z));
  const uint16_t h2=bfr(s2), l2=bfr(s2-bff(h2));
  union{ ushort u[16]; uint4 v[2]; } B;
  B.u[0]=hx; B.u[1]=hy; B.u[2]=hz; B.u[3]=lx; B.u[4]=ly; B.u[5]=lz;
  B.u[6]=hx; B.u[7]=hy; B.u[8]=hz; B.u[9]=lx; B.u[10]=ly; B.u[11]=lz;
  B.u[12]=0x3F80; B.u[13]=0x3F80; B.u[14]=h2; B.u[15]=l2;
  return B.v[half];
}

// ---------------- prep: pack target (A) and query (B) k-half planes ----------
__global__ __launch_bounds__(256) void prep_kernel(
    const float* __restrict__ pred, const float* __restrict__ gt,
    float* __restrict__ out, uint8_t* __restrict__ ws) {
  const int tid = blockIdx.x*256 + (int)threadIdx.x;   // 0..65535
  if (tid == 0) out[0] = 0.0f;
  const int col  = tid & 8191;
  const int half = (tid >> 13) & 1;
  const int db   = tid >> 14;          // dir*2 + b
  const int dir = db >> 1, b = db & 1;

  // dir0: queries=pred, targets=gt.  dir1: queries=gt, targets=pred.
  const float* tsrc = (dir == 0 ? gt : pred) + ((size_t)b*NP + col)*3;
  const float* qsrc = (dir == 0 ? pred : gt) + ((size_t)b*NP + col)*3;

  ((uint4*)(ws + OFF_A))[tid] = packA(tsrc[0], tsrc[1], tsrc[2], half);
  ((uint4*)(ws + OFF_B))[tid] = packB(qsrc[0], qsrc[1], qsrc[2], half);
}

// ---------------- main MFMA kernel ----------------
__global__ __launch_bounds__(256, 2) void chamfer_mfma_kernel(uint8_t* __restrict__ ws) {
  const int wave = threadIdx.x >> 6, lane = threadIdx.x & 63;
  const int half = lane >> 5, l31 = lane & 31;
  const int qblk  = blockIdx.x;             // 0..31 (256 queries per block)
  const int chunk = blockIdx.y;             // 0..7  (1024 targets per chunk)
  const int db    = blockIdx.z;             // dir*2 + b

  __shared__ uint4 ldsA[2][CHUNKCOLS];      // 32 KB target planes

  // ---- stage this chunk's target planes (both k-halves)
  const uint4* AP = (const uint4*)(ws + OFF_A) + (size_t)db*2*NP
                    + (size_t)chunk*CHUNKCOLS;
#pragma unroll
  for (int k = 0; k < 8; ++k) {
    const int gidx = k*256 + (int)threadIdx.x;   // 0..2047
    const int h = gidx >> 10, c = gidx & 1023;
    ((uint4*)ldsA)[gidx] = AP[(size_t)h*NP + c];
  }

  // ---- the wave's 64 queries: two fixed B-fragments (L2-hot global reads)
  const uint4* BP = (const uint4*)(ws + OFF_B) + (size_t)db*2*NP + (size_t)half*NP;
  const int qbase = qblk*256 + wave*64;
  const short8v bfrag0 = *(const short8v*)&BP[qbase + l31];
  const short8v bfrag1 = *(const short8v*)&BP[qbase + 32 + l31];

  float rm0 = 3.4e38f, rm1 = 3.4e38f;
  const f32x16 zero = {};

  __syncthreads();

  // ---- 32 tiles x {1 ds_read_b128 (targets), 2 MFMA, 16 v_min3}
  const uint4* la = &ldsA[half][l31];
#pragma unroll 2
  for (int t = 0; t < 32; ++t) {
    const short8v af = *(const short8v*)(la + t*32);
    const f32x16 m0 = __builtin_amdgcn_mfma_f32_32x32x16_bf16(af, bfrag0, zero, 0,0,0);
    const f32x16 m1 = __builtin_amdgcn_mfma_f32_32x32x16_bf16(af, bfrag1, zero, 0,0,0);
    rm0 = fold16(rm0, m0);
    rm1 = fold16(rm1, m1);
  }

  // ---- cross-half combine (both halves hold same query col) + store
  rm0 = fminf(rm0, __shfl_xor(rm0, 32));
  rm1 = fminf(rm1, __shfl_xor(rm1, 32));

  float* wr = (float*)(ws + OFF_ROW) + ((size_t)db*NCHUNK + chunk)*NP + qbase;
  if (half == 0) wr[l31]      = rm0;
  else           wr[32 + l31] = rm1;
}

// ---------------- final reduce ----------------
__global__ __launch_bounds__(256) void reduce_kernel(
    const uint8_t* __restrict__ ws, float* __restrict__ out) {
  const float* WROW = (const float*)(ws + OFF_ROW);
  const int tid = blockIdx.x*256 + (int)threadIdx.x;  // 0..32767
  const int db = tid >> 13, q = tid & 8191;

  const float* pr = WROW + (size_t)db*NCHUNK*NP + q;
  float mn = 3.4e38f;
#pragma unroll
  for (int k = 0; k < NCHUNK; ++k) mn = fminf(mn, pr[(size_t)k*NP]);
  float sum = fmaxf(mn, 0.0f);  // clamp == ref's maximum(d2,0)

#pragma unroll
  for (int off=32; off>0; off>>=1) sum += __shfl_down(sum, off);
  __shared__ float red[4];
  if ((threadIdx.x & 63) == 0) red[threadIdx.x >> 6] = sum;
  __syncthreads();
  if (threadIdx.x == 0) atomicAdd(out, (red[0]+red[1]+red[2]+red[3]) * SCALE);
}

extern "C" void kernel_launch(void* const* d_in, const int* in_sizes, int n_in,
                              void* d_out, int out_size, void* d_ws, size_t ws_size,
                              hipStream_t stream) {
  const float* pred = (const float*)d_in[0];
  const float* gt = (const float*)d_in[1];
  float* out = (float*)d_out;
  uint8_t* ws = (uint8_t*)d_ws;

  prep_kernel<<<256, 256, 0, stream>>>(pred, gt, out, ws);
  chamfer_mfma_kernel<<<dim3(32, NCHUNK, 4), 256, 0, stream>>>(ws);
  reduce_kernel<<<128, 256, 0, stream>>>(ws, out);
}